// Round 6
// baseline (271.935 us; speedup 1.0000x reference)
//
#include <hip/hip_runtime.h>
#include <hip/hip_bf16.h>

#define NN 40000
#define NN64 40064          // 626 * 64, padded row count for A tiles
#define EE 640000
#define CAP 64              // bucket capacity (in-deg ~ Poisson(16); P(>64) ~ 1e-22)

typedef __attribute__((ext_vector_type(8))) short short8;
typedef __attribute__((ext_vector_type(4))) float floatx4;

__device__ inline unsigned short f2bf(float f) {
    unsigned u = __float_as_uint(f);
    unsigned r = (u + 0x7FFFu + ((u >> 16) & 1u)) >> 16;
    return (unsigned short)r;
}
__device__ inline float bflo(unsigned u) { return __uint_as_float(u << 16); }
__device__ inline float bfhi(unsigned u) { return __uint_as_float(u & 0xFFFF0000u); }

// ---- fused: xyb = bf16(x+emb[y]) (padded), weight pack, cursor zero --------
__global__ void prep_kernel(const float4* __restrict__ x, const int* __restrict__ y,
                            const float4* __restrict__ emb,
                            const float* __restrict__ Wq, const float* __restrict__ Wk,
                            const float* __restrict__ Wv, const float* __restrict__ Ws,
                            uint2* __restrict__ xyb, unsigned short* __restrict__ Wp,
                            int* __restrict__ cursor) {
    int idx = blockIdx.x * 256 + threadIdx.x;          // over NN64*32 slots
    if (idx < NN64 * 32) {
        int n  = idx >> 5;
        int fo = idx & 31;
        uint2 o;
        if (n < NN) {
            float4 a = x[idx];
            float4 b = emb[y[n] * 32 + fo];
            unsigned t0 = f2bf(a.x + b.x), t1 = f2bf(a.y + b.y);
            unsigned t2 = f2bf(a.z + b.z), t3 = f2bf(a.w + b.w);
            o.x = t0 | (t1 << 16);
            o.y = t2 | (t3 << 16);
        } else {
            o.x = 0; o.y = 0;
        }
        xyb[idx] = o;
    }
    if (idx < 65536) {                                 // Wp[mode][n][k] = bf16(W[k][n]*s)
        int mode = idx >> 14;
        int r = idx & 16383;
        int n = r >> 7, k = r & 127;
        const float* W = (mode == 0) ? Wq : (mode == 1) ? Wk : (mode == 2) ? Wv : Ws;
        float val = W[k * 128 + n];
        if (mode == 0) val *= 0.17677669529663687f;    // fold 1/sqrt(D) into Wq
        Wp[idx] = f2bf(val);
    }
    if (idx < NN) cursor[idx] = 0;
}

// ---------------- MFMA projection GEMM -------------------------------------
// grid (626, 3); block 256 = 4 waves. Tile: 64 rows x 128 cols, K=128.
// y=0: q f32 (pre-scaled); y=1: ss f32; y=2: k then v -> kv dword (k|v<<16).
__global__ __launch_bounds__(256) void gemm_mfma(
    const unsigned short* __restrict__ Axy, const unsigned short* __restrict__ Wp,
    const float* __restrict__ bq, const float* __restrict__ bk,
    const float* __restrict__ bv, const float* __restrict__ bs,
    float* __restrict__ q, unsigned* __restrict__ kvd, float* __restrict__ ss) {
    __shared__ unsigned short As[64 * 136];            // 17,408 B

    int kind = blockIdx.y;
    long m0 = (long)blockIdx.x * 64;

    // stage A: 4 threads per row, 32 shorts = 4x uint4 (64 B) each
    {
        int t = threadIdx.x;
        int row = t >> 2, qtr = t & 3;
        const uint4* src = (const uint4*)(Axy + (m0 + row) * 128 + qtr * 32);
        uint4* dst = (uint4*)&As[row * 136 + qtr * 32];
#pragma unroll
        for (int i = 0; i < 4; ++i) dst[i] = src[i];
    }
    __syncthreads();

    int w  = threadIdx.x >> 6;                         // wave -> rows w*16..w*16+15
    int ln = threadIdx.x & 15;
    int qd = (threadIdx.x & 63) >> 4;

    short8 afr[4];
#pragma unroll
    for (int kc = 0; kc < 4; ++kc)
        afr[kc] = *(const short8*)&As[(w * 16 + ln) * 136 + kc * 32 + qd * 8];

    long rowb = m0 + w * 16 + qd * 4;

    if (kind < 2) {                                    // single f32-out GEMM (q or ss)
        int mode = (kind == 0) ? 0 : 3;
        const unsigned short* Wm = Wp + (size_t)mode * 16384;
        const float* bias = (kind == 0) ? bq : bs;
        float* C = (kind == 0) ? q : ss;
        float bscale = (kind == 0) ? 0.17677669529663687f : 1.0f;

        floatx4 acc[8];
#pragma unroll
        for (int ni = 0; ni < 8; ++ni) acc[ni] = (floatx4){0.f, 0.f, 0.f, 0.f};
#pragma unroll
        for (int kc = 0; kc < 4; ++kc) {
            short8 bfr[8];
#pragma unroll
            for (int ni = 0; ni < 8; ++ni)
                bfr[ni] = *(const short8*)&Wm[(ni * 16 + ln) * 128 + kc * 32 + qd * 8];
#pragma unroll
            for (int ni = 0; ni < 8; ++ni)
                acc[ni] = __builtin_amdgcn_mfma_f32_16x16x32_bf16(
                    afr[kc], bfr[ni], acc[ni], 0, 0, 0);
        }
#pragma unroll
        for (int ni = 0; ni < 8; ++ni) {
            int col = ni * 16 + ln;
            float bvv = bias[col] * bscale;
#pragma unroll
            for (int r = 0; r < 4; ++r) {
                long row = rowb + r;
                if (row < NN) C[row * 128 + col] = acc[ni][r] + bvv;
            }
        }
    } else {                                           // k then v, packed kv store
        const unsigned short* Wk16 = Wp + 16384;
        const unsigned short* Wv16 = Wp + 2 * 16384;

        floatx4 acc[8];
#pragma unroll
        for (int ni = 0; ni < 8; ++ni) acc[ni] = (floatx4){0.f, 0.f, 0.f, 0.f};
#pragma unroll
        for (int kc = 0; kc < 4; ++kc) {
            short8 bfr[8];
#pragma unroll
            for (int ni = 0; ni < 8; ++ni)
                bfr[ni] = *(const short8*)&Wk16[(ni * 16 + ln) * 128 + kc * 32 + qd * 8];
#pragma unroll
            for (int ni = 0; ni < 8; ++ni)
                acc[ni] = __builtin_amdgcn_mfma_f32_16x16x32_bf16(
                    afr[kc], bfr[ni], acc[ni], 0, 0, 0);
        }
        unsigned kp[8][4];
#pragma unroll
        for (int ni = 0; ni < 8; ++ni) {
            float bvv = bk[ni * 16 + ln];
#pragma unroll
            for (int r = 0; r < 4; ++r) kp[ni][r] = f2bf(acc[ni][r] + bvv);
        }
#pragma unroll
        for (int ni = 0; ni < 8; ++ni) acc[ni] = (floatx4){0.f, 0.f, 0.f, 0.f};
#pragma unroll
        for (int kc = 0; kc < 4; ++kc) {
            short8 bfr[8];
#pragma unroll
            for (int ni = 0; ni < 8; ++ni)
                bfr[ni] = *(const short8*)&Wv16[(ni * 16 + ln) * 128 + kc * 32 + qd * 8];
#pragma unroll
            for (int ni = 0; ni < 8; ++ni)
                acc[ni] = __builtin_amdgcn_mfma_f32_16x16x32_bf16(
                    afr[kc], bfr[ni], acc[ni], 0, 0, 0);
        }
#pragma unroll
        for (int ni = 0; ni < 8; ++ni) {
            int col = ni * 16 + ln;
            float bvv = bv[col];
#pragma unroll
            for (int r = 0; r < 4; ++r) {
                long row = rowb + r;
                if (row < NN)
                    kvd[row * 128 + col] = kp[ni][r] | ((unsigned)f2bf(acc[ni][r] + bvv) << 16);
            }
        }
    }
}

// ---------------- bucket CSR build ----------------
__global__ void fill_kernel(const int* __restrict__ ei, int* __restrict__ cursor,
                            int* __restrict__ csr) {
    int e = blockIdx.x * blockDim.x + threadIdx.x;
    if (e < EE) {
        int d = ei[EE + e];
        int s = ei[e];
        int pos = atomicAdd(&cursor[d], 1);
        if (pos < CAP) csr[(long)d * CAP + pos] = s;
    }
}

// -------- per-dst online-softmax attention + skip + fused classifier --------
// one 64-lane WAVE per dst node (4 nodes / 256-thread block);
// lane = (head = lane>>4, dimpair = lane&15): 2 dims per lane via uint2 kv.
// epilogue: agg row staged in LDS, each wave computes its node's 64 logits.
__global__ __launch_bounds__(256) void attn_kernel(
    const float* __restrict__ q, const unsigned* __restrict__ kv,
    const float* __restrict__ ss, const int* __restrict__ cursor,
    const int* __restrict__ csr, const float* __restrict__ Wl,
    const float* __restrict__ bl, float* __restrict__ out) {
    __shared__ float P[4][128];
    int w = threadIdx.x >> 6;
    int i = blockIdx.x * 4 + w;
    int lane = threadIdx.x & 63;
    int h = lane >> 4, dp = lane & 15;
    int base = i * 128 + h * 32 + 2 * dp;
    float2 qt = *(const float2*)&q[base];              // pre-scaled by 1/sqrt(D)
    int cnt = cursor[i];
    if (cnt > CAP) cnt = CAP;
    const int* lst = csr + (long)i * CAP;
    float m = -3.0e38f, l = 0.f, a0 = 0.f, a1 = 0.f;
    int p = 0;
    for (; p + 2 <= cnt; p += 2) {
        int j0 = lst[p], j1 = lst[p + 1];
        uint2 u0 = *(const uint2*)&kv[j0 * 128 + h * 32 + 2 * dp];
        uint2 u1 = *(const uint2*)&kv[j1 * 128 + h * 32 + 2 * dp];
        float pr0 = fmaf(qt.y, bflo(u0.y), qt.x * bflo(u0.x));
        float pr1 = fmaf(qt.y, bflo(u1.y), qt.x * bflo(u1.x));
#pragma unroll
        for (int s = 8; s; s >>= 1) {
            pr0 += __shfl_xor(pr0, s, 16);
            pr1 += __shfl_xor(pr1, s, 16);
        }
        float mnew = fmaxf(m, fmaxf(pr0, pr1));
        float sc = __expf(m - mnew);
        float e0 = __expf(pr0 - mnew), e1 = __expf(pr1 - mnew);
        l  = l * sc + e0 + e1;
        a0 = fmaf(e1, bfhi(u1.x), fmaf(e0, bfhi(u0.x), a0 * sc));
        a1 = fmaf(e1, bfhi(u1.y), fmaf(e0, bfhi(u0.y), a1 * sc));
        m = mnew;
    }
    if (p < cnt) {
        int j0 = lst[p];
        uint2 u0 = *(const uint2*)&kv[j0 * 128 + h * 32 + 2 * dp];
        float pr0 = fmaf(qt.y, bflo(u0.y), qt.x * bflo(u0.x));
#pragma unroll
        for (int s = 8; s; s >>= 1) pr0 += __shfl_xor(pr0, s, 16);
        float mnew = fmaxf(m, pr0);
        float sc = __expf(m - mnew);
        float e0 = __expf(pr0 - mnew);
        l  = l * sc + e0;
        a0 = fmaf(e0, bfhi(u0.x), a0 * sc);
        a1 = fmaf(e0, bfhi(u0.y), a1 * sc);
        m = mnew;
    }
    float inv = (l > 0.f) ? (1.0f / l) : 0.f;
    float2 s2 = *(const float2*)&ss[base];
    int pc = h * 32 + 2 * dp;
    P[w][pc]     = a0 * inv + s2.x;
    P[w][pc + 1] = a1 * inv + s2.y;
    __syncthreads();

    // fused classifier: wave w computes out[i][0..63], lane = col
    const float* Prow = P[w];
    int col = lane;
    float s0 = 0.f, s1 = 0.f, s2c = 0.f, s3 = 0.f;
#pragma unroll 4
    for (int k0 = 0; k0 < 128; k0 += 4) {
        s0 = fmaf(Prow[k0],     Wl[(k0)     * 64 + col], s0);
        s1 = fmaf(Prow[k0 + 1], Wl[(k0 + 1) * 64 + col], s1);
        s2c = fmaf(Prow[k0 + 2], Wl[(k0 + 2) * 64 + col], s2c);
        s3 = fmaf(Prow[k0 + 3], Wl[(k0 + 3) * 64 + col], s3);
    }
    out[(long)i * 64 + col] = (s0 + s1) + (s2c + s3) + bl[col];
}

extern "C" void kernel_launch(void* const* d_in, const int* in_sizes, int n_in,
                              void* d_out, int out_size, void* d_ws, size_t ws_size,
                              hipStream_t stream) {
    const float* x   = (const float*)d_in[0];
    const int*   y   = (const int*)d_in[1];
    const int*   ei  = (const int*)d_in[2];
    const float* emb = (const float*)d_in[3];
    const float* Wq  = (const float*)d_in[4];  const float* bq = (const float*)d_in[5];
    const float* Wk  = (const float*)d_in[6];  const float* bk = (const float*)d_in[7];
    const float* Wv  = (const float*)d_in[8];  const float* bv = (const float*)d_in[9];
    const float* Wsk = (const float*)d_in[10]; const float* bs = (const float*)d_in[11];
    const float* Wl  = (const float*)d_in[12]; const float* bl = (const float*)d_in[13];
    float* out = (float*)d_out;

    char* w = (char*)d_ws;
    float*          q    = (float*)(w);                          // 20,480,000
    float*          ss   = (float*)(w + 20480000);               // 20,480,000
    unsigned*       kv   = (unsigned*)(w + 40960000);            // 20,480,000
    unsigned short* xyb  = (unsigned short*)(w + 81920000);      // 10,256,384 (NN64 rows)
    int*            csr  = (int*)(w + 92176384);                 // 10,240,000
    unsigned short* Wp   = (unsigned short*)(w + 102416384);     //    131,072
    int*         cursor  = (int*)(w + 102547456);                //    160,000

    prep_kernel<<<NN64 * 32 / 256, 256, 0, stream>>>(
        (const float4*)x, y, (const float4*)emb, Wq, Wk, Wv, Wsk,
        (uint2*)xyb, Wp, cursor);
    dim3 gg(NN64 / 64, 3);
    gemm_mfma<<<gg, 256, 0, stream>>>(xyb, Wp, bq, bk, bv, bs, q, kv, ss);
    fill_kernel<<<(EE + 255) / 256, 256, 0, stream>>>(ei, cursor, csr);
    attn_kernel<<<NN / 4, 256, 0, stream>>>(q, kv, ss, cursor, csr, Wl, bl, out);
}

// Round 7
// 233.031 us; speedup vs baseline: 1.1669x; 1.1669x over previous
//
#include <hip/hip_runtime.h>
#include <hip/hip_bf16.h>

#define NN 40000
#define NN64 40064          // 626 * 64, padded row count for A tiles
#define EE 640000
#define CAP 64              // bucket capacity (in-deg ~ Poisson(16); P(>64) ~ 1e-22)

typedef __attribute__((ext_vector_type(8))) short short8;
typedef __attribute__((ext_vector_type(4))) float floatx4;

__device__ inline unsigned short f2bf(float f) {
    unsigned u = __float_as_uint(f);
    unsigned r = (u + 0x7FFFu + ((u >> 16) & 1u)) >> 16;
    return (unsigned short)r;
}
__device__ inline float bflo(unsigned u) { return __uint_as_float(u << 16); }
__device__ inline float bfhi(unsigned u) { return __uint_as_float(u & 0xFFFF0000u); }

// ---- fused: xyb = bf16(x+emb[y]) (padded), weight pack, cursor zero --------
__global__ void prep_kernel(const float4* __restrict__ x, const int* __restrict__ y,
                            const float4* __restrict__ emb,
                            const float* __restrict__ Wq, const float* __restrict__ Wk,
                            const float* __restrict__ Wv, const float* __restrict__ Ws,
                            uint2* __restrict__ xyb, unsigned short* __restrict__ Wp,
                            int* __restrict__ cursor) {
    int idx = blockIdx.x * 256 + threadIdx.x;          // over NN64*32 slots
    if (idx < NN64 * 32) {
        int n  = idx >> 5;
        int fo = idx & 31;
        uint2 o;
        if (n < NN) {
            float4 a = x[idx];
            float4 b = emb[y[n] * 32 + fo];
            unsigned t0 = f2bf(a.x + b.x), t1 = f2bf(a.y + b.y);
            unsigned t2 = f2bf(a.z + b.z), t3 = f2bf(a.w + b.w);
            o.x = t0 | (t1 << 16);
            o.y = t2 | (t3 << 16);
        } else {
            o.x = 0; o.y = 0;
        }
        xyb[idx] = o;
    }
    if (idx < 65536) {                                 // Wp[mode][n][k] = bf16(W[k][n]*s)
        int mode = idx >> 14;
        int r = idx & 16383;
        int n = r >> 7, k = r & 127;
        const float* W = (mode == 0) ? Wq : (mode == 1) ? Wk : (mode == 2) ? Wv : Ws;
        float val = W[k * 128 + n];
        if (mode == 0) val *= 0.17677669529663687f;    // fold 1/sqrt(D) into Wq
        Wp[idx] = f2bf(val);
    }
    if (idx < NN) cursor[idx] = 0;
}

// ------------- MFMA projection GEMM + concurrent CSR fill -------------------
// grid (626, 4); block 256 = 4 waves. Tile: 64 rows x 128 cols, K=128.
// y=0: q f32 (pre-scaled); y=1: ss f32; y=2: k then v -> kv dword (k|v<<16);
// y=3: bucket-CSR fill over edges (no GEMM work).
__global__ __launch_bounds__(256) void gemm_mfma(
    const unsigned short* __restrict__ Axy, const unsigned short* __restrict__ Wp,
    const float* __restrict__ bq, const float* __restrict__ bk,
    const float* __restrict__ bv, const float* __restrict__ bs,
    float* __restrict__ q, unsigned* __restrict__ kvd, float* __restrict__ ss,
    const int* __restrict__ ei, int* __restrict__ cursor, int* __restrict__ csr) {
    int kind = blockIdx.y;
    if (kind == 3) {                                   // CSR fill, grid-stride
        int t = blockIdx.x * 256 + threadIdx.x;        // 626*256 = 160,256 threads
        for (int e = t; e < EE; e += 626 * 256) {
            int d = ei[EE + e];
            int s = ei[e];
            int pos = atomicAdd(&cursor[d], 1);
            if (pos < CAP) csr[(long)d * CAP + pos] = s;
        }
        return;
    }

    __shared__ unsigned short As[64 * 136];            // 17,408 B
    long m0 = (long)blockIdx.x * 64;

    // stage A: 4 threads per row, 32 shorts = 4x uint4 (64 B) each
    {
        int t = threadIdx.x;
        int row = t >> 2, qtr = t & 3;
        const uint4* src = (const uint4*)(Axy + (m0 + row) * 128 + qtr * 32);
        uint4* dst = (uint4*)&As[row * 136 + qtr * 32];
#pragma unroll
        for (int i = 0; i < 4; ++i) dst[i] = src[i];
    }
    __syncthreads();

    int w  = threadIdx.x >> 6;                         // wave -> rows w*16..w*16+15
    int ln = threadIdx.x & 15;
    int qd = (threadIdx.x & 63) >> 4;

    short8 afr[4];
#pragma unroll
    for (int kc = 0; kc < 4; ++kc)
        afr[kc] = *(const short8*)&As[(w * 16 + ln) * 136 + kc * 32 + qd * 8];

    long rowb = m0 + w * 16 + qd * 4;

    if (kind < 2) {                                    // single f32-out GEMM (q or ss)
        int mode = (kind == 0) ? 0 : 3;
        const unsigned short* Wm = Wp + (size_t)mode * 16384;
        const float* bias = (kind == 0) ? bq : bs;
        float* C = (kind == 0) ? q : ss;
        float bscale = (kind == 0) ? 0.17677669529663687f : 1.0f;

        floatx4 acc[8];
#pragma unroll
        for (int ni = 0; ni < 8; ++ni) acc[ni] = (floatx4){0.f, 0.f, 0.f, 0.f};
#pragma unroll
        for (int kc = 0; kc < 4; ++kc) {
            short8 bfr[8];
#pragma unroll
            for (int ni = 0; ni < 8; ++ni)
                bfr[ni] = *(const short8*)&Wm[(ni * 16 + ln) * 128 + kc * 32 + qd * 8];
#pragma unroll
            for (int ni = 0; ni < 8; ++ni)
                acc[ni] = __builtin_amdgcn_mfma_f32_16x16x32_bf16(
                    afr[kc], bfr[ni], acc[ni], 0, 0, 0);
        }
#pragma unroll
        for (int ni = 0; ni < 8; ++ni) {
            int col = ni * 16 + ln;
            float bvv = bias[col] * bscale;
#pragma unroll
            for (int r = 0; r < 4; ++r) {
                long row = rowb + r;
                if (row < NN) C[row * 128 + col] = acc[ni][r] + bvv;
            }
        }
    } else {                                           // k then v, packed kv store
        const unsigned short* Wk16 = Wp + 16384;
        const unsigned short* Wv16 = Wp + 2 * 16384;

        floatx4 acc[8];
#pragma unroll
        for (int ni = 0; ni < 8; ++ni) acc[ni] = (floatx4){0.f, 0.f, 0.f, 0.f};
#pragma unroll
        for (int kc = 0; kc < 4; ++kc) {
            short8 bfr[8];
#pragma unroll
            for (int ni = 0; ni < 8; ++ni)
                bfr[ni] = *(const short8*)&Wk16[(ni * 16 + ln) * 128 + kc * 32 + qd * 8];
#pragma unroll
            for (int ni = 0; ni < 8; ++ni)
                acc[ni] = __builtin_amdgcn_mfma_f32_16x16x32_bf16(
                    afr[kc], bfr[ni], acc[ni], 0, 0, 0);
        }
        unsigned kp[8][4];
#pragma unroll
        for (int ni = 0; ni < 8; ++ni) {
            float bvv = bk[ni * 16 + ln];
#pragma unroll
            for (int r = 0; r < 4; ++r) kp[ni][r] = f2bf(acc[ni][r] + bvv);
        }
#pragma unroll
        for (int ni = 0; ni < 8; ++ni) acc[ni] = (floatx4){0.f, 0.f, 0.f, 0.f};
#pragma unroll
        for (int kc = 0; kc < 4; ++kc) {
            short8 bfr[8];
#pragma unroll
            for (int ni = 0; ni < 8; ++ni)
                bfr[ni] = *(const short8*)&Wv16[(ni * 16 + ln) * 128 + kc * 32 + qd * 8];
#pragma unroll
            for (int ni = 0; ni < 8; ++ni)
                acc[ni] = __builtin_amdgcn_mfma_f32_16x16x32_bf16(
                    afr[kc], bfr[ni], acc[ni], 0, 0, 0);
        }
#pragma unroll
        for (int ni = 0; ni < 8; ++ni) {
            int col = ni * 16 + ln;
            float bvv = bv[col];
#pragma unroll
            for (int r = 0; r < 4; ++r) {
                long row = rowb + r;
                if (row < NN)
                    kvd[row * 128 + col] = kp[ni][r] | ((unsigned)f2bf(acc[ni][r] + bvv) << 16);
            }
        }
    }
}

// -------- per-dst online-softmax attention + skip + k-split classifier ------
// one 64-lane WAVE per dst node (4 nodes / 256-thread block);
// lane = (head = lane>>4, dimpair = lane&15): 2 dims per lane via uint2 kv.
// classifier: P[4][128] in LDS; wave w handles k-slice [w*32,w*32+32) for ALL
// 4 nodes (Wl loaded once per (k,col), reused 4x), then LDS cross-wave reduce.
__global__ __launch_bounds__(256) void attn_kernel(
    const float* __restrict__ q, const unsigned* __restrict__ kv,
    const float* __restrict__ ss, const int* __restrict__ cursor,
    const int* __restrict__ csr, const float* __restrict__ Wl,
    const float* __restrict__ bl, float* __restrict__ out) {
    __shared__ float P[4][128];
    __shared__ float red[4][4][64];                    // [wave][node][col]
    int w = threadIdx.x >> 6;
    int i = blockIdx.x * 4 + w;
    int lane = threadIdx.x & 63;
    int h = lane >> 4, dp = lane & 15;
    int base = i * 128 + h * 32 + 2 * dp;
    float2 qt = *(const float2*)&q[base];              // pre-scaled by 1/sqrt(D)
    int cnt = cursor[i];
    if (cnt > CAP) cnt = CAP;
    const int* lst = csr + (long)i * CAP;
    float m = -3.0e38f, l = 0.f, a0 = 0.f, a1 = 0.f;
    int p = 0;
    for (; p + 4 <= cnt; p += 4) {
        int4 j4 = *(const int4*)&lst[p];
        uint2 u0 = *(const uint2*)&kv[j4.x * 128 + h * 32 + 2 * dp];
        uint2 u1 = *(const uint2*)&kv[j4.y * 128 + h * 32 + 2 * dp];
        uint2 u2 = *(const uint2*)&kv[j4.z * 128 + h * 32 + 2 * dp];
        uint2 u3 = *(const uint2*)&kv[j4.w * 128 + h * 32 + 2 * dp];
        float pr0 = fmaf(qt.y, bflo(u0.y), qt.x * bflo(u0.x));
        float pr1 = fmaf(qt.y, bflo(u1.y), qt.x * bflo(u1.x));
        float pr2 = fmaf(qt.y, bflo(u2.y), qt.x * bflo(u2.x));
        float pr3 = fmaf(qt.y, bflo(u3.y), qt.x * bflo(u3.x));
#pragma unroll
        for (int s = 8; s; s >>= 1) {
            pr0 += __shfl_xor(pr0, s, 16);
            pr1 += __shfl_xor(pr1, s, 16);
            pr2 += __shfl_xor(pr2, s, 16);
            pr3 += __shfl_xor(pr3, s, 16);
        }
        float mnew = fmaxf(fmaxf(m, fmaxf(pr0, pr1)), fmaxf(pr2, pr3));
        float sc = __expf(m - mnew);
        float e0 = __expf(pr0 - mnew), e1 = __expf(pr1 - mnew);
        float e2 = __expf(pr2 - mnew), e3 = __expf(pr3 - mnew);
        l  = l * sc + (e0 + e1) + (e2 + e3);
        a0 = fmaf(e3, bfhi(u3.x), fmaf(e2, bfhi(u2.x),
             fmaf(e1, bfhi(u1.x), fmaf(e0, bfhi(u0.x), a0 * sc))));
        a1 = fmaf(e3, bfhi(u3.y), fmaf(e2, bfhi(u2.y),
             fmaf(e1, bfhi(u1.y), fmaf(e0, bfhi(u0.y), a1 * sc))));
        m = mnew;
    }
    for (; p < cnt; ++p) {
        int j0 = lst[p];
        uint2 u0 = *(const uint2*)&kv[j0 * 128 + h * 32 + 2 * dp];
        float pr0 = fmaf(qt.y, bflo(u0.y), qt.x * bflo(u0.x));
#pragma unroll
        for (int s = 8; s; s >>= 1) pr0 += __shfl_xor(pr0, s, 16);
        float mnew = fmaxf(m, pr0);
        float sc = __expf(m - mnew);
        float e0 = __expf(pr0 - mnew);
        l  = l * sc + e0;
        a0 = fmaf(e0, bfhi(u0.x), a0 * sc);
        a1 = fmaf(e0, bfhi(u0.y), a1 * sc);
        m = mnew;
    }
    float inv = (l > 0.f) ? (1.0f / l) : 0.f;
    float2 s2 = *(const float2*)&ss[base];
    int pc = h * 32 + 2 * dp;
    P[w][pc]     = a0 * inv + s2.x;
    P[w][pc + 1] = a1 * inv + s2.y;
    __syncthreads();

    // k-split classifier: wave w, lane = col; k-slice [w*32, w*32+32)
    {
        int col = lane;
        const float* WlW = Wl + (size_t)(w * 32) * 64 + col;
        float c0 = 0.f, c1 = 0.f, c2 = 0.f, c3 = 0.f;
#pragma unroll
        for (int kk = 0; kk < 32; kk += 4) {
            int k = w * 32 + kk;
            float4 p0 = *(const float4*)&P[0][k];
            float4 p1 = *(const float4*)&P[1][k];
            float4 p2 = *(const float4*)&P[2][k];
            float4 p3 = *(const float4*)&P[3][k];
            float wl0 = WlW[(kk + 0) * 64];
            float wl1 = WlW[(kk + 1) * 64];
            float wl2 = WlW[(kk + 2) * 64];
            float wl3 = WlW[(kk + 3) * 64];
            c0 = fmaf(p0.w, wl3, fmaf(p0.z, wl2, fmaf(p0.y, wl1, fmaf(p0.x, wl0, c0))));
            c1 = fmaf(p1.w, wl3, fmaf(p1.z, wl2, fmaf(p1.y, wl1, fmaf(p1.x, wl0, c1))));
            c2 = fmaf(p2.w, wl3, fmaf(p2.z, wl2, fmaf(p2.y, wl1, fmaf(p2.x, wl0, c2))));
            c3 = fmaf(p3.w, wl3, fmaf(p3.z, wl2, fmaf(p3.y, wl1, fmaf(p3.x, wl0, c3))));
        }
        red[w][0][col] = c0;
        red[w][1][col] = c1;
        red[w][2][col] = c2;
        red[w][3][col] = c3;
    }
    __syncthreads();

    {
        int n = threadIdx.x >> 6;                      // node within block
        int col = threadIdx.x & 63;
        float s = red[0][n][col] + red[1][n][col] + red[2][n][col] + red[3][n][col];
        out[(long)(blockIdx.x * 4 + n) * 64 + col] = s + bl[col];
    }
}

extern "C" void kernel_launch(void* const* d_in, const int* in_sizes, int n_in,
                              void* d_out, int out_size, void* d_ws, size_t ws_size,
                              hipStream_t stream) {
    const float* x   = (const float*)d_in[0];
    const int*   y   = (const int*)d_in[1];
    const int*   ei  = (const int*)d_in[2];
    const float* emb = (const float*)d_in[3];
    const float* Wq  = (const float*)d_in[4];  const float* bq = (const float*)d_in[5];
    const float* Wk  = (const float*)d_in[6];  const float* bk = (const float*)d_in[7];
    const float* Wv  = (const float*)d_in[8];  const float* bv = (const float*)d_in[9];
    const float* Wsk = (const float*)d_in[10]; const float* bs = (const float*)d_in[11];
    const float* Wl  = (const float*)d_in[12]; const float* bl = (const float*)d_in[13];
    float* out = (float*)d_out;

    char* w = (char*)d_ws;
    float*          q    = (float*)(w);                          // 20,480,000
    float*          ss   = (float*)(w + 20480000);               // 20,480,000
    unsigned*       kv   = (unsigned*)(w + 40960000);            // 20,480,000
    unsigned short* xyb  = (unsigned short*)(w + 81920000);      // 10,256,384 (NN64 rows)
    int*            csr  = (int*)(w + 92176384);                 // 10,240,000
    unsigned short* Wp   = (unsigned short*)(w + 102416384);     //    131,072
    int*         cursor  = (int*)(w + 102547456);                //    160,000

    prep_kernel<<<NN64 * 32 / 256, 256, 0, stream>>>(
        (const float4*)x, y, (const float4*)emb, Wq, Wk, Wv, Wsk,
        (uint2*)xyb, Wp, cursor);
    dim3 gg(NN64 / 64, 4);
    gemm_mfma<<<gg, 256, 0, stream>>>(xyb, Wp, bq, bk, bv, bs, q, kv, ss,
                                      ei, cursor, csr);
    attn_kernel<<<NN / 4, 256, 0, stream>>>(q, kv, ss, cursor, csr, Wl, bl, out);
}

// Round 8
// 223.048 us; speedup vs baseline: 1.2192x; 1.0448x over previous
//
#include <hip/hip_runtime.h>
#include <hip/hip_bf16.h>

#define NN 40000
#define NN64 40064          // 626 * 64, padded row count for A tiles
#define EE 640000
#define CAP 64              // bucket capacity (in-deg ~ Poisson(16); P(>64) ~ 1e-22)

typedef __attribute__((ext_vector_type(8))) short short8;
typedef __attribute__((ext_vector_type(4))) float floatx4;

__device__ inline unsigned short f2bf(float f) {
    unsigned u = __float_as_uint(f);
    unsigned r = (u + 0x7FFFu + ((u >> 16) & 1u)) >> 16;
    return (unsigned short)r;
}
__device__ inline float bflo(unsigned u) { return __uint_as_float(u << 16); }
__device__ inline float bfhi(unsigned u) { return __uint_as_float(u & 0xFFFF0000u); }

// ---- fused: xyb = bf16(x+emb[y]) (padded), weight pack, cursor zero --------
__global__ void prep_kernel(const float4* __restrict__ x, const int* __restrict__ y,
                            const float4* __restrict__ emb,
                            const float* __restrict__ Wq, const float* __restrict__ Wk,
                            const float* __restrict__ Wv, const float* __restrict__ Ws,
                            uint2* __restrict__ xyb, unsigned short* __restrict__ Wp,
                            int* __restrict__ cursor) {
    int idx = blockIdx.x * 256 + threadIdx.x;          // over NN64*32 slots
    if (idx < NN64 * 32) {
        int n  = idx >> 5;
        int fo = idx & 31;
        uint2 o;
        if (n < NN) {
            float4 a = x[idx];
            float4 b = emb[y[n] * 32 + fo];
            unsigned t0 = f2bf(a.x + b.x), t1 = f2bf(a.y + b.y);
            unsigned t2 = f2bf(a.z + b.z), t3 = f2bf(a.w + b.w);
            o.x = t0 | (t1 << 16);
            o.y = t2 | (t3 << 16);
        } else {
            o.x = 0; o.y = 0;
        }
        xyb[idx] = o;
    }
    if (idx < 65536) {                                 // Wp[mode][n][k] = bf16(W[k][n]*s)
        int mode = idx >> 14;
        int r = idx & 16383;
        int n = r >> 7, k = r & 127;
        const float* W = (mode == 0) ? Wq : (mode == 1) ? Wk : (mode == 2) ? Wv : Ws;
        float val = W[k * 128 + n];
        if (mode == 0) val *= 0.17677669529663687f;    // fold 1/sqrt(D) into Wq
        Wp[idx] = f2bf(val);
    }
    if (idx < NN) cursor[idx] = 0;
}

// ------------- MFMA projection GEMM + concurrent CSR fill -------------------
// grid (626, 3); block 256 = 4 waves. Tile: 64 rows x 128 cols, K=128.
// y=0: q then ss -> qss dword (bf16(q*s) | bf16(ss)<<16)
// y=1: k then v  -> kv  dword (bf16(k)   | bf16(v)<<16)
// y=2: bucket-CSR fill over edges (no GEMM work).
__global__ __launch_bounds__(256) void gemm_mfma(
    const unsigned short* __restrict__ Axy, const unsigned short* __restrict__ Wp,
    const float* __restrict__ bq, const float* __restrict__ bk,
    const float* __restrict__ bv, const float* __restrict__ bs,
    unsigned* __restrict__ qss, unsigned* __restrict__ kvd,
    const int* __restrict__ ei, int* __restrict__ cursor, int* __restrict__ csr) {
    int kind = blockIdx.y;
    if (kind == 2) {                                   // CSR fill, grid-stride
        int t = blockIdx.x * 256 + threadIdx.x;        // 626*256 = 160,256 threads
        for (int e = t; e < EE; e += 626 * 256) {
            int d = ei[EE + e];
            int s = ei[e];
            int pos = atomicAdd(&cursor[d], 1);
            if (pos < CAP) csr[(long)d * CAP + pos] = s;
        }
        return;
    }

    __shared__ unsigned short As[64 * 136];            // 17,408 B
    long m0 = (long)blockIdx.x * 64;

    // stage A: 4 threads per row, 32 shorts = 4x uint4 (64 B) each
    {
        int t = threadIdx.x;
        int row = t >> 2, qtr = t & 3;
        const uint4* src = (const uint4*)(Axy + (m0 + row) * 128 + qtr * 32);
        uint4* dst = (uint4*)&As[row * 136 + qtr * 32];
#pragma unroll
        for (int i = 0; i < 4; ++i) dst[i] = src[i];
    }
    __syncthreads();

    int w  = threadIdx.x >> 6;                         // wave -> rows w*16..w*16+15
    int ln = threadIdx.x & 15;
    int qd = (threadIdx.x & 63) >> 4;

    short8 afr[4];
#pragma unroll
    for (int kc = 0; kc < 4; ++kc)
        afr[kc] = *(const short8*)&As[(w * 16 + ln) * 136 + kc * 32 + qd * 8];

    long rowb = m0 + w * 16 + qd * 4;

    const unsigned short* Wm1 = Wp + (size_t)((kind == 0) ? 0 : 1) * 16384;
    const unsigned short* Wm2 = Wp + (size_t)((kind == 0) ? 3 : 2) * 16384;
    const float* b1 = (kind == 0) ? bq : bk;
    const float* b2 = (kind == 0) ? bs : bv;
    float b1s = (kind == 0) ? 0.17677669529663687f : 1.0f;
    unsigned* dst = (kind == 0) ? qss : kvd;

    floatx4 acc[8];
#pragma unroll
    for (int ni = 0; ni < 8; ++ni) acc[ni] = (floatx4){0.f, 0.f, 0.f, 0.f};
#pragma unroll
    for (int kc = 0; kc < 4; ++kc) {
        short8 bfr[8];
#pragma unroll
        for (int ni = 0; ni < 8; ++ni)
            bfr[ni] = *(const short8*)&Wm1[(ni * 16 + ln) * 128 + kc * 32 + qd * 8];
#pragma unroll
        for (int ni = 0; ni < 8; ++ni)
            acc[ni] = __builtin_amdgcn_mfma_f32_16x16x32_bf16(
                afr[kc], bfr[ni], acc[ni], 0, 0, 0);
    }
    unsigned lo[8][4];                                 // bf16 stash of first GEMM
#pragma unroll
    for (int ni = 0; ni < 8; ++ni) {
        float bvv = b1[ni * 16 + ln] * b1s;
#pragma unroll
        for (int r = 0; r < 4; ++r) lo[ni][r] = f2bf(acc[ni][r] + bvv);
    }
#pragma unroll
    for (int ni = 0; ni < 8; ++ni) acc[ni] = (floatx4){0.f, 0.f, 0.f, 0.f};
#pragma unroll
    for (int kc = 0; kc < 4; ++kc) {
        short8 bfr[8];
#pragma unroll
        for (int ni = 0; ni < 8; ++ni)
            bfr[ni] = *(const short8*)&Wm2[(ni * 16 + ln) * 128 + kc * 32 + qd * 8];
#pragma unroll
        for (int ni = 0; ni < 8; ++ni)
            acc[ni] = __builtin_amdgcn_mfma_f32_16x16x32_bf16(
                afr[kc], bfr[ni], acc[ni], 0, 0, 0);
    }
#pragma unroll
    for (int ni = 0; ni < 8; ++ni) {
        int col = ni * 16 + ln;
        float bvv = b2[col];
#pragma unroll
        for (int r = 0; r < 4; ++r) {
            long row = rowb + r;
            if (row < NN)
                dst[row * 128 + col] = lo[ni][r] | ((unsigned)f2bf(acc[ni][r] + bvv) << 16);
        }
    }
}

// -------- per-dst online-softmax attention + skip + k-split classifier ------
// one 64-lane WAVE per dst node (4 nodes / 256-thread block);
// lane = (head = lane>>4, dimpair = lane&15): 2 dims per lane via uint2 kv.
// q and ss come packed in qss (q bf16 low, ss bf16 high).
// classifier: P[4][128] in LDS; wave w handles k-slice [w*32,w*32+32) for ALL
// 4 nodes (Wl loaded once per (k,col), reused 4x), then LDS cross-wave reduce.
__global__ __launch_bounds__(256) void attn_kernel(
    const unsigned* __restrict__ qss, const unsigned* __restrict__ kv,
    const int* __restrict__ cursor, const int* __restrict__ csr,
    const float* __restrict__ Wl, const float* __restrict__ bl,
    float* __restrict__ out) {
    __shared__ float P[4][128];
    __shared__ float red[4][4][64];                    // [wave][node][col]
    int w = threadIdx.x >> 6;
    int i = blockIdx.x * 4 + w;
    int lane = threadIdx.x & 63;
    int h = lane >> 4, dp = lane & 15;
    int base = i * 128 + h * 32 + 2 * dp;
    uint2 qsu = *(const uint2*)&qss[base];
    float2 qt;                                         // pre-scaled by 1/sqrt(D)
    qt.x = bflo(qsu.x); qt.y = bflo(qsu.y);
    int cnt = cursor[i];
    if (cnt > CAP) cnt = CAP;
    const int* lst = csr + (long)i * CAP;
    float m = -3.0e38f, l = 0.f, a0 = 0.f, a1 = 0.f;
    int p = 0;
    for (; p + 8 <= cnt; p += 8) {
        int4 ja = *(const int4*)&lst[p];
        int4 jb = *(const int4*)&lst[p + 4];
        uint2 u0 = *(const uint2*)&kv[ja.x * 128 + h * 32 + 2 * dp];
        uint2 u1 = *(const uint2*)&kv[ja.y * 128 + h * 32 + 2 * dp];
        uint2 u2 = *(const uint2*)&kv[ja.z * 128 + h * 32 + 2 * dp];
        uint2 u3 = *(const uint2*)&kv[ja.w * 128 + h * 32 + 2 * dp];
        uint2 u4 = *(const uint2*)&kv[jb.x * 128 + h * 32 + 2 * dp];
        uint2 u5 = *(const uint2*)&kv[jb.y * 128 + h * 32 + 2 * dp];
        uint2 u6 = *(const uint2*)&kv[jb.z * 128 + h * 32 + 2 * dp];
        uint2 u7 = *(const uint2*)&kv[jb.w * 128 + h * 32 + 2 * dp];
        float pr0 = fmaf(qt.y, bflo(u0.y), qt.x * bflo(u0.x));
        float pr1 = fmaf(qt.y, bflo(u1.y), qt.x * bflo(u1.x));
        float pr2 = fmaf(qt.y, bflo(u2.y), qt.x * bflo(u2.x));
        float pr3 = fmaf(qt.y, bflo(u3.y), qt.x * bflo(u3.x));
        float pr4 = fmaf(qt.y, bflo(u4.y), qt.x * bflo(u4.x));
        float pr5 = fmaf(qt.y, bflo(u5.y), qt.x * bflo(u5.x));
        float pr6 = fmaf(qt.y, bflo(u6.y), qt.x * bflo(u6.x));
        float pr7 = fmaf(qt.y, bflo(u7.y), qt.x * bflo(u7.x));
#pragma unroll
        for (int s = 8; s; s >>= 1) {
            pr0 += __shfl_xor(pr0, s, 16);
            pr1 += __shfl_xor(pr1, s, 16);
            pr2 += __shfl_xor(pr2, s, 16);
            pr3 += __shfl_xor(pr3, s, 16);
            pr4 += __shfl_xor(pr4, s, 16);
            pr5 += __shfl_xor(pr5, s, 16);
            pr6 += __shfl_xor(pr6, s, 16);
            pr7 += __shfl_xor(pr7, s, 16);
        }
        float mnew = fmaxf(fmaxf(fmaxf(m, fmaxf(pr0, pr1)), fmaxf(fmaxf(pr2, pr3), fmaxf(pr4, pr5))),
                           fmaxf(pr6, pr7));
        float sc = __expf(m - mnew);
        float e0 = __expf(pr0 - mnew), e1 = __expf(pr1 - mnew);
        float e2 = __expf(pr2 - mnew), e3 = __expf(pr3 - mnew);
        float e4 = __expf(pr4 - mnew), e5 = __expf(pr5 - mnew);
        float e6 = __expf(pr6 - mnew), e7 = __expf(pr7 - mnew);
        l  = l * sc + ((e0 + e1) + (e2 + e3)) + ((e4 + e5) + (e6 + e7));
        a0 = fmaf(e7, bfhi(u7.x), fmaf(e6, bfhi(u6.x), fmaf(e5, bfhi(u5.x), fmaf(e4, bfhi(u4.x),
             fmaf(e3, bfhi(u3.x), fmaf(e2, bfhi(u2.x),
             fmaf(e1, bfhi(u1.x), fmaf(e0, bfhi(u0.x), a0 * sc))))))));
        a1 = fmaf(e7, bfhi(u7.y), fmaf(e6, bfhi(u6.y), fmaf(e5, bfhi(u5.y), fmaf(e4, bfhi(u4.y),
             fmaf(e3, bfhi(u3.y), fmaf(e2, bfhi(u2.y),
             fmaf(e1, bfhi(u1.y), fmaf(e0, bfhi(u0.y), a1 * sc))))))));
        m = mnew;
    }
    for (; p + 4 <= cnt; p += 4) {
        int4 j4 = *(const int4*)&lst[p];
        uint2 u0 = *(const uint2*)&kv[j4.x * 128 + h * 32 + 2 * dp];
        uint2 u1 = *(const uint2*)&kv[j4.y * 128 + h * 32 + 2 * dp];
        uint2 u2 = *(const uint2*)&kv[j4.z * 128 + h * 32 + 2 * dp];
        uint2 u3 = *(const uint2*)&kv[j4.w * 128 + h * 32 + 2 * dp];
        float pr0 = fmaf(qt.y, bflo(u0.y), qt.x * bflo(u0.x));
        float pr1 = fmaf(qt.y, bflo(u1.y), qt.x * bflo(u1.x));
        float pr2 = fmaf(qt.y, bflo(u2.y), qt.x * bflo(u2.x));
        float pr3 = fmaf(qt.y, bflo(u3.y), qt.x * bflo(u3.x));
#pragma unroll
        for (int s = 8; s; s >>= 1) {
            pr0 += __shfl_xor(pr0, s, 16);
            pr1 += __shfl_xor(pr1, s, 16);
            pr2 += __shfl_xor(pr2, s, 16);
            pr3 += __shfl_xor(pr3, s, 16);
        }
        float mnew = fmaxf(fmaxf(m, fmaxf(pr0, pr1)), fmaxf(pr2, pr3));
        float sc = __expf(m - mnew);
        float e0 = __expf(pr0 - mnew), e1 = __expf(pr1 - mnew);
        float e2 = __expf(pr2 - mnew), e3 = __expf(pr3 - mnew);
        l  = l * sc + (e0 + e1) + (e2 + e3);
        a0 = fmaf(e3, bfhi(u3.x), fmaf(e2, bfhi(u2.x),
             fmaf(e1, bfhi(u1.x), fmaf(e0, bfhi(u0.x), a0 * sc))));
        a1 = fmaf(e3, bfhi(u3.y), fmaf(e2, bfhi(u2.y),
             fmaf(e1, bfhi(u1.y), fmaf(e0, bfhi(u0.y), a1 * sc))));
        m = mnew;
    }
    for (; p < cnt; ++p) {
        int j0 = lst[p];
        uint2 u0 = *(const uint2*)&kv[j0 * 128 + h * 32 + 2 * dp];
        float pr0 = fmaf(qt.y, bflo(u0.y), qt.x * bflo(u0.x));
#pragma unroll
        for (int s = 8; s; s >>= 1) pr0 += __shfl_xor(pr0, s, 16);
        float mnew = fmaxf(m, pr0);
        float sc = __expf(m - mnew);
        float e0 = __expf(pr0 - mnew);
        l  = l * sc + e0;
        a0 = fmaf(e0, bfhi(u0.x), a0 * sc);
        a1 = fmaf(e0, bfhi(u0.y), a1 * sc);
        m = mnew;
    }
    float inv = (l > 0.f) ? (1.0f / l) : 0.f;
    int pc = h * 32 + 2 * dp;
    P[w][pc]     = a0 * inv + bfhi(qsu.x);
    P[w][pc + 1] = a1 * inv + bfhi(qsu.y);
    __syncthreads();

    // k-split classifier: wave w, lane = col; k-slice [w*32, w*32+32)
    {
        int col = lane;
        const float* WlW = Wl + (size_t)(w * 32) * 64 + col;
        float c0 = 0.f, c1 = 0.f, c2 = 0.f, c3 = 0.f;
#pragma unroll
        for (int kk = 0; kk < 32; kk += 4) {
            int k = w * 32 + kk;
            float4 p0 = *(const float4*)&P[0][k];
            float4 p1 = *(const float4*)&P[1][k];
            float4 p2 = *(const float4*)&P[2][k];
            float4 p3 = *(const float4*)&P[3][k];
            float wl0 = WlW[(kk + 0) * 64];
            float wl1 = WlW[(kk + 1) * 64];
            float wl2 = WlW[(kk + 2) * 64];
            float wl3 = WlW[(kk + 3) * 64];
            c0 = fmaf(p0.w, wl3, fmaf(p0.z, wl2, fmaf(p0.y, wl1, fmaf(p0.x, wl0, c0))));
            c1 = fmaf(p1.w, wl3, fmaf(p1.z, wl2, fmaf(p1.y, wl1, fmaf(p1.x, wl0, c1))));
            c2 = fmaf(p2.w, wl3, fmaf(p2.z, wl2, fmaf(p2.y, wl1, fmaf(p2.x, wl0, c2))));
            c3 = fmaf(p3.w, wl3, fmaf(p3.z, wl2, fmaf(p3.y, wl1, fmaf(p3.x, wl0, c3))));
        }
        red[w][0][col] = c0;
        red[w][1][col] = c1;
        red[w][2][col] = c2;
        red[w][3][col] = c3;
    }
    __syncthreads();

    {
        int n = threadIdx.x >> 6;                      // node within block
        int col = threadIdx.x & 63;
        float s = red[0][n][col] + red[1][n][col] + red[2][n][col] + red[3][n][col];
        out[(long)(blockIdx.x * 4 + n) * 64 + col] = s + bl[col];
    }
}

extern "C" void kernel_launch(void* const* d_in, const int* in_sizes, int n_in,
                              void* d_out, int out_size, void* d_ws, size_t ws_size,
                              hipStream_t stream) {
    const float* x   = (const float*)d_in[0];
    const int*   y   = (const int*)d_in[1];
    const int*   ei  = (const int*)d_in[2];
    const float* emb = (const float*)d_in[3];
    const float* Wq  = (const float*)d_in[4];  const float* bq = (const float*)d_in[5];
    const float* Wk  = (const float*)d_in[6];  const float* bk = (const float*)d_in[7];
    const float* Wv  = (const float*)d_in[8];  const float* bv = (const float*)d_in[9];
    const float* Wsk = (const float*)d_in[10]; const float* bs = (const float*)d_in[11];
    const float* Wl  = (const float*)d_in[12]; const float* bl = (const float*)d_in[13];
    float* out = (float*)d_out;

    char* w = (char*)d_ws;
    unsigned*       qss  = (unsigned*)(w);                       // 20,480,000
    unsigned*       kv   = (unsigned*)(w + 20480000);            // 20,480,000
    unsigned short* xyb  = (unsigned short*)(w + 40960000);      // 10,256,384 (NN64 rows)
    int*            csr  = (int*)(w + 51216384);                 // 10,240,000
    unsigned short* Wp   = (unsigned short*)(w + 61456384);      //    131,072
    int*         cursor  = (int*)(w + 61587456);                 //    160,000

    prep_kernel<<<NN64 * 32 / 256, 256, 0, stream>>>(
        (const float4*)x, y, (const float4*)emb, Wq, Wk, Wv, Wsk,
        (uint2*)xyb, Wp, cursor);
    dim3 gg(NN64 / 64, 3);
    gemm_mfma<<<gg, 256, 0, stream>>>(xyb, Wp, bq, bk, bv, bs, qss, kv,
                                      ei, cursor, csr);
    attn_kernel<<<NN / 4, 256, 0, stream>>>(qss, kv, cursor, csr, Wl, bl, out);
}